// Round 6
// baseline (153.761 us; speedup 1.0000x reference)
//
#include <hip/hip_runtime.h>
#include <math.h>

#define SEQ    2048
#define DMODEL 1024
#define NHEADS 16
#define DHEAD  64
#define NBATCH 2

typedef __attribute__((ext_vector_type(8)))  short bf16x8;
typedef __attribute__((ext_vector_type(4)))  float f32x4;
typedef __attribute__((ext_vector_type(16))) float f32x16;

__device__ __forceinline__ unsigned short f2bf(float f) {
    union { float f; unsigned u; } v; v.f = f;
    unsigned r = (v.u + 0x7FFF + ((v.u >> 16) & 1)) >> 16;
    return (unsigned short)r;
}

__device__ __forceinline__ unsigned cvt_pk_bf16(float lo, float hi) {
    unsigned r;
    asm("v_cvt_pk_bf16_f32 %0, %1, %2" : "=v"(r) : "v"(lo), "v"(hi));
    return r;
}

// async global->LDS, 16B per lane (HW: wave-uniform LDS base + lane*16;
// global src is per-lane).
__device__ __forceinline__ void gload16(const void* g, void* l) {
    __builtin_amdgcn_global_load_lds(
        (const __attribute__((address_space(1))) unsigned*)g,
        (__attribute__((address_space(3))) unsigned*)l, 16, 0, 0);
}

// ---------------------------------------------------------------------------
// Cast fp32 -> bf16, flat contiguous. 8 elems/thread.
// ---------------------------------------------------------------------------
__global__ __launch_bounds__(256)
void cast_bf16_kernel(const float* __restrict__ in, unsigned short* __restrict__ out) {
    const size_t g8 = ((size_t)blockIdx.x * 256 + threadIdx.x) * 8;
    float4 a = *reinterpret_cast<const float4*>(in + g8);
    float4 b = *reinterpret_cast<const float4*>(in + g8 + 4);
    bf16x8 o;
    o[0] = (short)f2bf(a.x); o[1] = (short)f2bf(a.y);
    o[2] = (short)f2bf(a.z); o[3] = (short)f2bf(a.w);
    o[4] = (short)f2bf(b.x); o[5] = (short)f2bf(b.y);
    o[6] = (short)f2bf(b.z); o[7] = (short)f2bf(b.w);
    *reinterpret_cast<bf16x8*>(out + g8) = o;
}

// ---------------------------------------------------------------------------
// Transpose-cast a 1024x1024 fp32 weight [K][N] -> bf16 [N][K].
// ---------------------------------------------------------------------------
__global__ __launch_bounds__(256)
void wt_cast_kernel(const float* __restrict__ W, unsigned short* __restrict__ Wt) {
    __shared__ float tile[64][65];
    const int nt  = blockIdx.x & 15;
    const int kt  = blockIdx.x >> 4;
    const int tid = threadIdx.x;

#pragma unroll
    for (int r = 0; r < 4; ++r) {
        int kl = r * 16 + (tid >> 4);
        int nl = (tid & 15) * 4;
        float4 v = *reinterpret_cast<const float4*>(
            &W[(size_t)(kt * 64 + kl) * 1024 + nt * 64 + nl]);
        tile[kl][nl + 0] = v.x; tile[kl][nl + 1] = v.y;
        tile[kl][nl + 2] = v.z; tile[kl][nl + 3] = v.w;
    }
    __syncthreads();

    const int n  = tid >> 2;
    const int kc = (tid & 3) * 16;
    bf16x8 o0, o1;
#pragma unroll
    for (int i = 0; i < 8; ++i) o0[i] = (short)f2bf(tile[kc + i][n]);
#pragma unroll
    for (int i = 0; i < 8; ++i) o1[i] = (short)f2bf(tile[kc + 8 + i][n]);
    unsigned short* op = Wt + (size_t)(nt * 64 + n) * 1024 + kt * 64 + kc;
    *reinterpret_cast<bf16x8*>(op)     = o0;
    *reinterpret_cast<bf16x8*>(op + 8) = o1;
}

// ---------------------------------------------------------------------------
// bf16 MFMA GEMM, m97 structure: C = A @ Bt^T (+bias)
// 128x128 tile, BK=32, global_load_lds(16B) staging into linear LDS [128][32]
// with chunk-XOR swizzle (chunk ^= (row>>1)&3) applied on BOTH the per-lane
// global source and the ds_read offset (involution). 2 barriers per K-step.
// ---------------------------------------------------------------------------
template <int MODE>
__global__ __launch_bounds__(256)
void gemm_bf16(const unsigned short* __restrict__ A,
               const unsigned short* __restrict__ Bt,
               const float* __restrict__ bias0, const float* __restrict__ bias1,
               const float* __restrict__ bias2,
               float* __restrict__ Cf,
               unsigned short* __restrict__ Qo, unsigned short* __restrict__ Ko,
               unsigned short* __restrict__ Vo,
               int M, int N, int K) {
    __shared__ unsigned short As[128 * 32];
    __shared__ unsigned short Bs[128 * 32];

    const int tid  = threadIdx.x;
    const int bm   = blockIdx.y * 128;
    const int bn   = blockIdx.x * 128;
    const int w    = tid >> 6;
    const int lane = tid & 63;
    const int lrow = lane & 15;
    const int lk   = lane >> 4;
    const int wm0  = (w >> 1) * 64;
    const int wn0  = (w & 1) * 64;

    // staging geometry: thread covers 16B chunks at boff0 (rows 0..63) and
    // boff1 (rows 64..127) of each 8KB half-tile.
    const int boff0 = tid * 16;               // bytes into As/Bs
    const int boff1 = 4096 + tid * 16;
    const int row0  = tid >> 2;               // 0..63
    const int row1  = 64 + row0;
    const int c     = tid & 3;                // logical 16B chunk in row
    const int sw0   = (c ^ ((row0 >> 1) & 3)) * 8;  // shorts
    const int sw1   = (c ^ ((row1 >> 1) & 3)) * 8;

    const unsigned short* Ag = A  + (size_t)bm * K;
    const unsigned short* Bg = Bt + (size_t)bn * K;

    f32x4 acc[4][4];
#pragma unroll
    for (int i = 0; i < 4; ++i)
#pragma unroll
        for (int j = 0; j < 4; ++j) acc[i][j] = (f32x4){0.f, 0.f, 0.f, 0.f};

    const int NT = K / 32;
    for (int kt = 0; kt < NT; ++kt) {
        const int k0 = kt * 32;
        gload16(Ag + (size_t)row0 * K + k0 + sw0, (char*)As + boff0);
        gload16(Ag + (size_t)row1 * K + k0 + sw1, (char*)As + boff1);
        gload16(Bg + (size_t)row0 * K + k0 + sw0, (char*)Bs + boff0);
        gload16(Bg + (size_t)row1 * K + k0 + sw1, (char*)Bs + boff1);
        __syncthreads();   // compiler drains vmcnt before barrier

        bf16x8 af[4], bf[4];
#pragma unroll
        for (int mg = 0; mg < 4; ++mg) {
            const int r = wm0 + mg * 16 + lrow;
            af[mg] = *reinterpret_cast<const bf16x8*>(
                (char*)As + r * 64 + ((lk ^ ((r >> 1) & 3)) * 16));
        }
#pragma unroll
        for (int ng = 0; ng < 4; ++ng) {
            const int r = wn0 + ng * 16 + lrow;
            bf[ng] = *reinterpret_cast<const bf16x8*>(
                (char*)Bs + r * 64 + ((lk ^ ((r >> 1) & 3)) * 16));
        }
#pragma unroll
        for (int mg = 0; mg < 4; ++mg)
#pragma unroll
            for (int ng = 0; ng < 4; ++ng)
                acc[mg][ng] = __builtin_amdgcn_mfma_f32_16x16x32_bf16(
                    af[mg], bf[ng], acc[mg][ng], 0, 0, 0);
        __syncthreads();
    }

    if (MODE == 0) {
        const int type = bn >> 10;                 // 0=Q 1=K 2=V
        const int nloc = bn & 1023;
        const float* bias = (type == 0) ? bias0 : (type == 1) ? bias1 : bias2;
        // Q scale: 1/8 (1/sqrt(Dh)) * log2(e)  -> softmax runs in exp2 domain
        const float QSCALE = 0.125f * 1.44269504088896f;
#pragma unroll
        for (int ng = 0; ng < 4; ++ng) {
            const int col = nloc + wn0 + ng * 16 + lrow;
            const float bv = bias[col];
            const int h = col >> 6, d = col & 63;
#pragma unroll
            for (int mg = 0; mg < 4; ++mg) {
#pragma unroll
                for (int j = 0; j < 4; ++j) {
                    const int row = bm + wm0 + mg * 16 + (lane >> 4) * 4 + j;
                    const int b = row >> 11, s = row & 2047;
                    const float val = acc[mg][ng][j] + bv;
                    if (type == 0)
                        Qo[((size_t)(b * 16 + h) * SEQ + s) * 64 + d] = f2bf(val * QSCALE);
                    else if (type == 1)
                        Ko[((size_t)(b * 16 + h) * SEQ + s) * 64 + d] = f2bf(val);
                    else
                        Vo[((size_t)(b * 16 + h) * 64 + d) * SEQ + s] = f2bf(val);
                }
            }
        }
    } else {
#pragma unroll
        for (int ng = 0; ng < 4; ++ng) {
            const int col = bn + wn0 + ng * 16 + lrow;
            const float bv = bias0[col];
#pragma unroll
            for (int mg = 0; mg < 4; ++mg) {
#pragma unroll
                for (int j = 0; j < 4; ++j) {
                    const int row = bm + wm0 + mg * 16 + (lane >> 4) * 4 + j;
                    Cf[(size_t)row * N + col] = acc[mg][ng][j] + bv;
                }
            }
        }
    }
}

// ---------------------------------------------------------------------------
// Causal flash attention, swapped-operand 32x32x16 MFMA.
// R6: XCD-aware block mapping (all 16 q-blocks of a head on one XCD ->
// K/V L2-resident, load latency hidden by the existing prefetch);
// softmax fmax tree + 4-way ls accumulators (shorter serial chains).
// ---------------------------------------------------------------------------
__global__ __launch_bounds__(256)
void attn_mfma_kernel(const unsigned short* __restrict__ Qg,
                      const unsigned short* __restrict__ Kg,
                      const unsigned short* __restrict__ Vtg,
                      unsigned short* __restrict__ CTX) {
    __shared__ __align__(16) unsigned short Ks[2][64 * 64];   // [buf][key][dim] swz
    __shared__ __align__(16) unsigned short Vt[2][64 * 64];   // [buf][dim][key] swz

    // bid%8 -> XCD (round-robin heuristic). Keep one head's 16 blocks on one
    // XCD; alternate small/big q-blocks so consecutive slots sum to 34 tiles.
    const int bid  = blockIdx.x;          // 0..511
    const int xcd  = bid & 7;
    const int slot = bid >> 3;            // 0..63
    const int bh   = (slot >> 4) * 8 + xcd;              // 0..31
    const int rb_i = slot & 15;
    const int rb   = (rb_i & 1) ? (15 - (rb_i >> 1)) : (rb_i >> 1);  // bijective
    const int b  = bh >> 4;
    const int h  = bh & 15;
    const int r0 = rb * 128;
    const int tid  = threadIdx.x;
    const int w    = tid >> 6;
    const int lane = tid & 63;
    const int qcol = lane & 31;
    const int hlf  = lane >> 5;
    const int wr0  = r0 + w * 32;
    const int qrow = wr0 + qcol;

    const unsigned short* Kb = Kg + ((size_t)bh * SEQ) * DHEAD;
    const unsigned short* Vb = Vtg + ((size_t)bh * DHEAD) * SEQ;

    // Q fragment (B-operand)
    bf16x8 qf[4];
    {
        const unsigned short* qp = Qg + ((size_t)bh * SEQ + qrow) * DHEAD + hlf * 8;
#pragma unroll
        for (int ksub = 0; ksub < 4; ++ksub)
            qf[ksub] = *reinterpret_cast<const bf16x8*>(qp + ksub * 16);
    }

    f32x16 O0, O1;
#pragma unroll
    for (int r = 0; r < 16; ++r) { O0[r] = 0.f; O1[r] = 0.f; }
    float m = -1e30f, l = 0.f;

    const int srow = tid >> 2;           // 0..63
    const int c0   = (tid & 3) * 16;     // shorts
    const int sb0  = srow * 128 + ((c0 * 2) ^ ((srow & 7) << 4));
    const int sb1  = srow * 128 + (((c0 + 8) * 2) ^ ((srow & 7) << 4));

    // prologue: load tile 0 into regs
    bf16x8 rk0, rk1, rv0, rv1;
    {
        const unsigned short* kp = Kb + (size_t)srow * DHEAD + c0;
        const unsigned short* vp = Vb + (size_t)srow * SEQ + c0;
        rk0 = *reinterpret_cast<const bf16x8*>(kp);
        rk1 = *reinterpret_cast<const bf16x8*>(kp + 8);
        rv0 = *reinterpret_cast<const bf16x8*>(vp);
        rv1 = *reinterpret_cast<const bf16x8*>(vp + 8);
    }

    const int ntile = (r0 + 128) / 64;
    for (int t = 0; t < ntile; ++t) {
        const int j0 = t * 64;
        const int buf = t & 1;
        // ---- commit staged regs to LDS[buf] ----
        *reinterpret_cast<bf16x8*>((char*)&Ks[buf][0] + sb0) = rk0;
        *reinterpret_cast<bf16x8*>((char*)&Ks[buf][0] + sb1) = rk1;
        *reinterpret_cast<bf16x8*>((char*)&Vt[buf][0] + sb0) = rv0;
        *reinterpret_cast<bf16x8*>((char*)&Vt[buf][0] + sb1) = rv1;
        __syncthreads();
        // ---- issue next tile's global loads (latency hides under compute) ----
        if (t + 1 < ntile) {
            const int j1 = j0 + 64;
            const unsigned short* kp = Kb + (size_t)(j1 + srow) * DHEAD + c0;
            const unsigned short* vp = Vb + (size_t)srow * SEQ + j1 + c0;
            rk0 = *reinterpret_cast<const bf16x8*>(kp);
            rk1 = *reinterpret_cast<const bf16x8*>(kp + 8);
            rv0 = *reinterpret_cast<const bf16x8*>(vp);
            rv1 = *reinterpret_cast<const bf16x8*>(vp + 8);
        }

        if (j0 <= wr0 + 31) {
            // ---- S^T = K * Q^T ----
            f32x16 S[2];
#pragma unroll
            for (int r = 0; r < 16; ++r) { S[0][r] = 0.f; S[1][r] = 0.f; }
            __builtin_amdgcn_s_setprio(1);
#pragma unroll
            for (int kb = 0; kb < 2; ++kb) {
                const int key = kb * 32 + qcol;
#pragma unroll
                for (int ksub = 0; ksub < 4; ++ksub) {
                    int boff = key * 128 + ((ksub * 32 + hlf * 16) ^ ((key & 7) << 4));
                    bf16x8 kf = *reinterpret_cast<const bf16x8*>((char*)&Ks[buf][0] + boff);
                    S[kb] = __builtin_amdgcn_mfma_f32_32x32x16_bf16(
                        kf, qf[ksub], S[kb], 0, 0, 0);
                }
            }
            __builtin_amdgcn_s_setprio(0);

            // ---- causal mask (boundary tiles only) ----
            if (j0 + 63 > wr0) {
#pragma unroll
                for (int kb = 0; kb < 2; ++kb)
#pragma unroll
                    for (int r = 0; r < 16; ++r) {
                        int ka = j0 + kb * 32 + (r & 3) + 8 * (r >> 2) + 4 * hlf;
                        if (ka > qrow) S[kb][r] = -1e30f;
                    }
            }

            // ---- softmax (exp2 domain): tree max, 1 shfl, 4-way sums ----
            float mx[8];
#pragma unroll
            for (int r = 0; r < 8; ++r)
                mx[r] = fmaxf(fmaxf(S[0][r], S[0][r + 8]),
                              fmaxf(S[1][r], S[1][r + 8]));
            float m01 = fmaxf(mx[0], mx[1]), m23 = fmaxf(mx[2], mx[3]);
            float m45 = fmaxf(mx[4], mx[5]), m67 = fmaxf(mx[6], mx[7]);
            float pm = fmaxf(fmaxf(m01, m23), fmaxf(m45, m67));
            pm = fmaxf(pm, __shfl_xor(pm, 32));

            if (__any(pm > m)) {
                float mnew = fmaxf(m, pm);
                float cor  = __builtin_amdgcn_exp2f(m - mnew);
                m = mnew;
                l *= cor;
#pragma unroll
                for (int r = 0; r < 16; ++r) { O0[r] *= cor; O1[r] *= cor; }
            }

            float l0 = 0.f, l1 = 0.f, l2 = 0.f, l3 = 0.f;
#pragma unroll
            for (int kb = 0; kb < 2; ++kb)
#pragma unroll
                for (int r = 0; r < 16; r += 4) {
                    float p0 = __builtin_amdgcn_exp2f(S[kb][r + 0] - m);
                    float p1 = __builtin_amdgcn_exp2f(S[kb][r + 1] - m);
                    float p2 = __builtin_amdgcn_exp2f(S[kb][r + 2] - m);
                    float p3 = __builtin_amdgcn_exp2f(S[kb][r + 3] - m);
                    S[kb][r + 0] = p0; S[kb][r + 1] = p1;
                    S[kb][r + 2] = p2; S[kb][r + 3] = p3;
                    l0 += p0; l1 += p1; l2 += p2; l3 += p3;
                }
            l += (l0 + l1) + (l2 + l3);

            // ---- PV: O^T += V^T * P^T (cvt_pk + permlane swap) ----
#pragma unroll
            for (int kc = 0; kc < 4; ++kc) {
                const int kb = kc >> 1;
                const int R0 = (kc & 1) * 8;
                unsigned pa = cvt_pk_bf16(S[kb][R0 + 0], S[kb][R0 + 1]);
                unsigned pc = cvt_pk_bf16(S[kb][R0 + 4], S[kb][R0 + 5]);
                asm("v_permlane32_swap_b32 %0, %1" : "+v"(pa), "+v"(pc));
                unsigned pb = cvt_pk_bf16(S[kb][R0 + 2], S[kb][R0 + 3]);
                unsigned pd = cvt_pk_bf16(S[kb][R0 + 6], S[kb][R0 + 7]);
                asm("v_permlane32_swap_b32 %0, %1" : "+v"(pb), "+v"(pd));
                union { unsigned u[4]; bf16x8 v; } pf;
                pf.u[0] = pa; pf.u[1] = pb; pf.u[2] = pc; pf.u[3] = pd;
                __builtin_amdgcn_s_setprio(1);
#pragma unroll
                for (int db = 0; db < 2; ++db) {
                    const int dim = db * 32 + qcol;
                    int boff = dim * 128 + ((kc * 32 + hlf * 16) ^ ((dim & 7) << 4));
                    bf16x8 vf = *reinterpret_cast<const bf16x8*>((char*)&Vt[buf][0] + boff);
                    if (db == 0)
                        O0 = __builtin_amdgcn_mfma_f32_32x32x16_bf16(vf, pf.v, O0, 0, 0, 0);
                    else
                        O1 = __builtin_amdgcn_mfma_f32_32x32x16_bf16(vf, pf.v, O1, 0, 0, 0);
                }
                __builtin_amdgcn_s_setprio(0);
            }
        }
    }

    // ---- epilogue ----
    l += __shfl_xor(l, 32);
    const float inv = 1.f / l;
    unsigned short* crow = CTX + ((size_t)(b * SEQ + qrow)) * DMODEL + h * DHEAD;
#pragma unroll
    for (int pq = 0; pq < 4; ++pq) {
        unsigned w0 = cvt_pk_bf16(O0[pq * 4 + 0] * inv, O0[pq * 4 + 1] * inv);
        unsigned w1 = cvt_pk_bf16(O0[pq * 4 + 2] * inv, O0[pq * 4 + 3] * inv);
        uint2 val; val.x = w0; val.y = w1;
        *reinterpret_cast<uint2*>(crow + 8 * pq + 4 * hlf) = val;
    }
#pragma unroll
    for (int pq = 0; pq < 4; ++pq) {
        unsigned w0 = cvt_pk_bf16(O1[pq * 4 + 0] * inv, O1[pq * 4 + 1] * inv);
        unsigned w1 = cvt_pk_bf16(O1[pq * 4 + 2] * inv, O1[pq * 4 + 3] * inv);
        uint2 val; val.x = w0; val.y = w1;
        *reinterpret_cast<uint2*>(crow + 32 + 8 * pq + 4 * hlf) = val;
    }
}

// ---------------------------------------------------------------------------
extern "C" void kernel_launch(void* const* d_in, const int* in_sizes, int n_in,
                              void* d_out, int out_size, void* d_ws, size_t ws_size,
                              hipStream_t stream) {
    const float* hs = (const float*)d_in[0];
    const float* Wq = (const float*)d_in[1];
    const float* bq = (const float*)d_in[2];
    const float* Wk = (const float*)d_in[3];
    const float* bk = (const float*)d_in[4];
    const float* Wv = (const float*)d_in[5];
    const float* bv = (const float*)d_in[6];
    const float* Wo = (const float*)d_in[7];
    const float* bo = (const float*)d_in[8];
    float* out = (float*)d_out;

    const size_t NTOK = (size_t)NBATCH * SEQ;        // 4096
    unsigned short* hs_bf  = (unsigned short*)d_ws;              // 8 MB
    unsigned short* Wqkv_t = hs_bf + NTOK * DMODEL;              // 6 MB [3072][1024]
    unsigned short* Wo_t   = Wqkv_t + 3072 * 1024;               // 2 MB [1024][1024]
    unsigned short* Qh     = Wo_t + 1024 * 1024;                 // 8 MB [B,H,S,64]
    unsigned short* Kh     = Qh + NTOK * DMODEL;                 // 8 MB
    unsigned short* Vt     = Kh + NTOK * DMODEL;                 // 8 MB [B,H,64,S]
    unsigned short* Cb     = Vt + NTOK * DMODEL;                 // 8 MB ctx bf16

    cast_bf16_kernel<<<(int)(NTOK * DMODEL / 8 / 256), 256, 0, stream>>>(hs, hs_bf);
    wt_cast_kernel<<<256, 256, 0, stream>>>(Wq, Wqkv_t);
    wt_cast_kernel<<<256, 256, 0, stream>>>(Wk, Wqkv_t + 1024 * 1024);
    wt_cast_kernel<<<256, 256, 0, stream>>>(Wv, Wqkv_t + 2 * 1024 * 1024);
    wt_cast_kernel<<<256, 256, 0, stream>>>(Wo, Wo_t);

    dim3 gqkv(3072 / 128, NTOK / 128);               // (24, 32)
    gemm_bf16<0><<<gqkv, 256, 0, stream>>>(hs_bf, Wqkv_t, bq, bk, bv,
                                           nullptr, Qh, Kh, Vt,
                                           (int)NTOK, 3072, DMODEL);

    attn_mfma_kernel<<<NBATCH * NHEADS * (SEQ / 128), 256, 0, stream>>>(Qh, Kh, Vt, Cb);

    dim3 go(DMODEL / 128, NTOK / 128);               // (8, 32)
    gemm_bf16<1><<<go, 256, 0, stream>>>(Cb, Wo_t, bo, nullptr, nullptr,
                                         out, nullptr, nullptr, nullptr,
                                         (int)NTOK, DMODEL, DMODEL);
}

// Round 7
// 134.781 us; speedup vs baseline: 1.1408x; 1.1408x over previous
//
#include <hip/hip_runtime.h>
#include <math.h>

#define SEQ    2048
#define DMODEL 1024
#define NHEADS 16
#define DHEAD  64
#define NBATCH 2

typedef __attribute__((ext_vector_type(8)))  short bf16x8;
typedef __attribute__((ext_vector_type(4)))  float f32x4;
typedef __attribute__((ext_vector_type(16))) float f32x16;

__device__ __forceinline__ unsigned short f2bf(float f) {
    union { float f; unsigned u; } v; v.f = f;
    unsigned r = (v.u + 0x7FFF + ((v.u >> 16) & 1)) >> 16;
    return (unsigned short)r;
}

__device__ __forceinline__ unsigned cvt_pk_bf16(float lo, float hi) {
    unsigned r;
    asm("v_cvt_pk_bf16_f32 %0, %1, %2" : "=v"(r) : "v"(lo), "v"(hi));
    return r;
}

// async global->LDS, 16B per lane (HW: wave-uniform LDS base + lane*16;
// global src is per-lane).
__device__ __forceinline__ void gload16(const void* g, void* l) {
    __builtin_amdgcn_global_load_lds(
        (const __attribute__((address_space(1))) unsigned*)g,
        (__attribute__((address_space(3))) unsigned*)l, 16, 0, 0);
}

// ---------------------------------------------------------------------------
// Cast fp32 -> bf16, flat contiguous. 8 elems/thread.
// ---------------------------------------------------------------------------
__global__ __launch_bounds__(256)
void cast_bf16_kernel(const float* __restrict__ in, unsigned short* __restrict__ out) {
    const size_t g8 = ((size_t)blockIdx.x * 256 + threadIdx.x) * 8;
    float4 a = *reinterpret_cast<const float4*>(in + g8);
    float4 b = *reinterpret_cast<const float4*>(in + g8 + 4);
    bf16x8 o;
    o[0] = (short)f2bf(a.x); o[1] = (short)f2bf(a.y);
    o[2] = (short)f2bf(a.z); o[3] = (short)f2bf(a.w);
    o[4] = (short)f2bf(b.x); o[5] = (short)f2bf(b.y);
    o[6] = (short)f2bf(b.z); o[7] = (short)f2bf(b.w);
    *reinterpret_cast<bf16x8*>(out + g8) = o;
}

// ---------------------------------------------------------------------------
// Transpose-cast all four 1024x1024 fp32 weights [K][N] -> bf16 [N][K]
// in ONE dispatch. blockIdx.y selects the weight; outputs are contiguous
// (Wqkv_t then Wo_t).
// ---------------------------------------------------------------------------
__global__ __launch_bounds__(256)
void wt_cast4_kernel(const float* __restrict__ W0, const float* __restrict__ W1,
                     const float* __restrict__ W2, const float* __restrict__ W3,
                     unsigned short* __restrict__ out) {
    __shared__ float tile[64][65];
    const int wsel = blockIdx.y;
    const float* W = (wsel == 0) ? W0 : (wsel == 1) ? W1 : (wsel == 2) ? W2 : W3;
    unsigned short* Wt = out + (size_t)wsel * 1024 * 1024;

    const int nt  = blockIdx.x & 15;
    const int kt  = blockIdx.x >> 4;
    const int tid = threadIdx.x;

#pragma unroll
    for (int r = 0; r < 4; ++r) {
        int kl = r * 16 + (tid >> 4);
        int nl = (tid & 15) * 4;
        float4 v = *reinterpret_cast<const float4*>(
            &W[(size_t)(kt * 64 + kl) * 1024 + nt * 64 + nl]);
        tile[kl][nl + 0] = v.x; tile[kl][nl + 1] = v.y;
        tile[kl][nl + 2] = v.z; tile[kl][nl + 3] = v.w;
    }
    __syncthreads();

    const int n  = tid >> 2;
    const int kc = (tid & 3) * 16;
    bf16x8 o0, o1;
#pragma unroll
    for (int i = 0; i < 8; ++i) o0[i] = (short)f2bf(tile[kc + i][n]);
#pragma unroll
    for (int i = 0; i < 8; ++i) o1[i] = (short)f2bf(tile[kc + 8 + i][n]);
    unsigned short* op = Wt + (size_t)(nt * 64 + n) * 1024 + kt * 64 + kc;
    *reinterpret_cast<bf16x8*>(op)     = o0;
    *reinterpret_cast<bf16x8*>(op + 8) = o1;
}

// ---------------------------------------------------------------------------
// bf16 MFMA GEMM: C = A @ Bt^T (+bias)
// 128x128 tile, BK=32, global_load_lds(16B) staging, DOUBLE-BUFFERED LDS,
// T3 minimum-2-phase: stage(buf^1) issued BEFORE ds_read+MFMA of buf; the
// single __syncthreads per K-step drains next-tile loads AFTER compute ->
// load latency hidden even at 1 block/CU. Chunk-XOR swizzle applied on both
// the per-lane global source and the ds_read offset (involution).
// ---------------------------------------------------------------------------
template <int MODE>
__global__ __launch_bounds__(256)
void gemm_bf16(const unsigned short* __restrict__ A,
               const unsigned short* __restrict__ Bt,
               const float* __restrict__ bias0, const float* __restrict__ bias1,
               const float* __restrict__ bias2,
               float* __restrict__ Cf,
               unsigned short* __restrict__ Qo, unsigned short* __restrict__ Ko,
               unsigned short* __restrict__ Vo,
               int M, int N, int K) {
    __shared__ unsigned short As[2][128 * 32];
    __shared__ unsigned short Bs[2][128 * 32];

    const int tid  = threadIdx.x;
    const int bm   = blockIdx.y * 128;
    const int bn   = blockIdx.x * 128;
    const int w    = tid >> 6;
    const int lane = tid & 63;
    const int lrow = lane & 15;
    const int lk   = lane >> 4;
    const int wm0  = (w >> 1) * 64;
    const int wn0  = (w & 1) * 64;

    // staging geometry
    const int boff0 = tid * 16;               // bytes into As/Bs half 0
    const int boff1 = 4096 + tid * 16;        // rows 64..127
    const int row0  = tid >> 2;               // 0..63
    const int row1  = 64 + row0;
    const int c     = tid & 3;                // logical 16B chunk in row
    const int sw0   = (c ^ ((row0 >> 1) & 3)) * 8;  // shorts
    const int sw1   = (c ^ ((row1 >> 1) & 3)) * 8;

    const unsigned short* Ag = A  + (size_t)bm * K;
    const unsigned short* Bg = Bt + (size_t)bn * K;

    f32x4 acc[4][4];
#pragma unroll
    for (int i = 0; i < 4; ++i)
#pragma unroll
        for (int j = 0; j < 4; ++j) acc[i][j] = (f32x4){0.f, 0.f, 0.f, 0.f};

    const int NT = K / 32;
    // prologue: stage tile 0 into buf 0
    {
        gload16(Ag + (size_t)row0 * K + sw0, (char*)&As[0][0] + boff0);
        gload16(Ag + (size_t)row1 * K + sw1, (char*)&As[0][0] + boff1);
        gload16(Bg + (size_t)row0 * K + sw0, (char*)&Bs[0][0] + boff0);
        gload16(Bg + (size_t)row1 * K + sw1, (char*)&Bs[0][0] + boff1);
    }
    __syncthreads();

    int buf = 0;
    for (int kt = 0; kt < NT; ++kt) {
        // issue next tile's stage first (flies during ds_read + MFMA)
        if (kt + 1 < NT) {
            const int k0 = (kt + 1) * 32;
            gload16(Ag + (size_t)row0 * K + k0 + sw0, (char*)&As[buf ^ 1][0] + boff0);
            gload16(Ag + (size_t)row1 * K + k0 + sw1, (char*)&As[buf ^ 1][0] + boff1);
            gload16(Bg + (size_t)row0 * K + k0 + sw0, (char*)&Bs[buf ^ 1][0] + boff0);
            gload16(Bg + (size_t)row1 * K + k0 + sw1, (char*)&Bs[buf ^ 1][0] + boff1);
        }

        bf16x8 af[4], bf[4];
#pragma unroll
        for (int mg = 0; mg < 4; ++mg) {
            const int r = wm0 + mg * 16 + lrow;
            af[mg] = *reinterpret_cast<const bf16x8*>(
                (char*)&As[buf][0] + r * 64 + ((lk ^ ((r >> 1) & 3)) * 16));
        }
#pragma unroll
        for (int ng = 0; ng < 4; ++ng) {
            const int r = wn0 + ng * 16 + lrow;
            bf[ng] = *reinterpret_cast<const bf16x8*>(
                (char*)&Bs[buf][0] + r * 64 + ((lk ^ ((r >> 1) & 3)) * 16));
        }
#pragma unroll
        for (int mg = 0; mg < 4; ++mg)
#pragma unroll
            for (int ng = 0; ng < 4; ++ng)
                acc[mg][ng] = __builtin_amdgcn_mfma_f32_16x16x32_bf16(
                    af[mg], bf[ng], acc[mg][ng], 0, 0, 0);

        __syncthreads();   // implicit vmcnt(0): next-tile stage completes here
        buf ^= 1;
    }

    if (MODE == 0) {
        const int type = bn >> 10;                 // 0=Q 1=K 2=V
        const int nloc = bn & 1023;
        const float* bias = (type == 0) ? bias0 : (type == 1) ? bias1 : bias2;
        // Q scale: 1/8 (1/sqrt(Dh)) * log2(e)  -> softmax runs in exp2 domain
        const float QSCALE = 0.125f * 1.44269504088896f;
#pragma unroll
        for (int ng = 0; ng < 4; ++ng) {
            const int col = nloc + wn0 + ng * 16 + lrow;
            const float bv = bias[col];
            const int h = col >> 6, d = col & 63;
#pragma unroll
            for (int mg = 0; mg < 4; ++mg) {
#pragma unroll
                for (int j = 0; j < 4; ++j) {
                    const int row = bm + wm0 + mg * 16 + lk * 4 + j;
                    const int b = row >> 11, s = row & 2047;
                    const float val = acc[mg][ng][j] + bv;
                    if (type == 0)
                        Qo[((size_t)(b * 16 + h) * SEQ + s) * 64 + d] = f2bf(val * QSCALE);
                    else if (type == 1)
                        Ko[((size_t)(b * 16 + h) * SEQ + s) * 64 + d] = f2bf(val);
                    else
                        Vo[((size_t)(b * 16 + h) * 64 + d) * SEQ + s] = f2bf(val);
                }
            }
        }
    } else {
#pragma unroll
        for (int ng = 0; ng < 4; ++ng) {
            const int col = bn + wn0 + ng * 16 + lrow;
            const float bv = bias0[col];
#pragma unroll
            for (int mg = 0; mg < 4; ++mg) {
#pragma unroll
                for (int j = 0; j < 4; ++j) {
                    const int row = bm + wm0 + mg * 16 + lk * 4 + j;
                    Cf[(size_t)row * N + col] = acc[mg][ng][j] + bv;
                }
            }
        }
    }
}

// ---------------------------------------------------------------------------
// Causal flash attention, swapped-operand 32x32x16 MFMA.
// R7 mapping: XCD head-grouping (4 heads per XCD -> K/V L2-resident, proven
// by R6 FETCH 55->12 MB) + EQUAL-size pairing (consecutive slots share a CU
// and get the same tile count -> full 8-wave TLP for the whole critical
// path; R6's small+big pairing collapsed TLP and cost +12us).
// ---------------------------------------------------------------------------
__global__ __launch_bounds__(256)
void attn_mfma_kernel(const unsigned short* __restrict__ Qg,
                      const unsigned short* __restrict__ Kg,
                      const unsigned short* __restrict__ Vtg,
                      unsigned short* __restrict__ CTX) {
    __shared__ __align__(16) unsigned short Ks[2][64 * 64];   // [buf][key][dim] swz
    __shared__ __align__(16) unsigned short Vt[2][64 * 64];   // [buf][dim][key] swz

    const int bid = blockIdx.x;           // 0..511
    const int xcd = bid & 7;
    const int s   = bid >> 3;             // 0..63
    const int bh  = xcd * 4 + (s & 3);    // 4 heads per XCD
    const int rb  = s >> 2;               // equal-rb on consecutive slots
    const int b  = bh >> 4;
    const int h  = bh & 15;
    const int r0 = rb * 128;
    const int tid  = threadIdx.x;
    const int w    = tid >> 6;
    const int lane = tid & 63;
    const int qcol = lane & 31;
    const int hlf  = lane >> 5;
    const int wr0  = r0 + w * 32;
    const int qrow = wr0 + qcol;

    const unsigned short* Kb = Kg + ((size_t)bh * SEQ) * DHEAD;
    const unsigned short* Vb = Vtg + ((size_t)bh * DHEAD) * SEQ;

    // Q fragment (B-operand)
    bf16x8 qf[4];
    {
        const unsigned short* qp = Qg + ((size_t)bh * SEQ + qrow) * DHEAD + hlf * 8;
#pragma unroll
        for (int ksub = 0; ksub < 4; ++ksub)
            qf[ksub] = *reinterpret_cast<const bf16x8*>(qp + ksub * 16);
    }

    f32x16 O0, O1;
#pragma unroll
    for (int r = 0; r < 16; ++r) { O0[r] = 0.f; O1[r] = 0.f; }
    float m = -1e30f, l = 0.f;

    const int srow = tid >> 2;           // 0..63
    const int c0   = (tid & 3) * 16;     // shorts
    const int sb0  = srow * 128 + ((c0 * 2) ^ ((srow & 7) << 4));
    const int sb1  = srow * 128 + (((c0 + 8) * 2) ^ ((srow & 7) << 4));

    // prologue: load tile 0 into regs
    bf16x8 rk0, rk1, rv0, rv1;
    {
        const unsigned short* kp = Kb + (size_t)srow * DHEAD + c0;
        const unsigned short* vp = Vb + (size_t)srow * SEQ + c0;
        rk0 = *reinterpret_cast<const bf16x8*>(kp);
        rk1 = *reinterpret_cast<const bf16x8*>(kp + 8);
        rv0 = *reinterpret_cast<const bf16x8*>(vp);
        rv1 = *reinterpret_cast<const bf16x8*>(vp + 8);
    }

    const int ntile = (r0 + 128) / 64;
    for (int t = 0; t < ntile; ++t) {
        const int j0 = t * 64;
        const int buf = t & 1;
        // ---- commit staged regs to LDS[buf] ----
        *reinterpret_cast<bf16x8*>((char*)&Ks[buf][0] + sb0) = rk0;
        *reinterpret_cast<bf16x8*>((char*)&Ks[buf][0] + sb1) = rk1;
        *reinterpret_cast<bf16x8*>((char*)&Vt[buf][0] + sb0) = rv0;
        *reinterpret_cast<bf16x8*>((char*)&Vt[buf][0] + sb1) = rv1;
        __syncthreads();
        // ---- issue next tile's global loads (latency hides under compute) ----
        if (t + 1 < ntile) {
            const int j1 = j0 + 64;
            const unsigned short* kp = Kb + (size_t)(j1 + srow) * DHEAD + c0;
            const unsigned short* vp = Vb + (size_t)srow * SEQ + j1 + c0;
            rk0 = *reinterpret_cast<const bf16x8*>(kp);
            rk1 = *reinterpret_cast<const bf16x8*>(kp + 8);
            rv0 = *reinterpret_cast<const bf16x8*>(vp);
            rv1 = *reinterpret_cast<const bf16x8*>(vp + 8);
        }

        if (j0 <= wr0 + 31) {
            // ---- S^T = K * Q^T ----
            f32x16 S[2];
#pragma unroll
            for (int r = 0; r < 16; ++r) { S[0][r] = 0.f; S[1][r] = 0.f; }
            __builtin_amdgcn_s_setprio(1);
#pragma unroll
            for (int kb = 0; kb < 2; ++kb) {
                const int key = kb * 32 + qcol;
#pragma unroll
                for (int ksub = 0; ksub < 4; ++ksub) {
                    int boff = key * 128 + ((ksub * 32 + hlf * 16) ^ ((key & 7) << 4));
                    bf16x8 kf = *reinterpret_cast<const bf16x8*>((char*)&Ks[buf][0] + boff);
                    S[kb] = __builtin_amdgcn_mfma_f32_32x32x16_bf16(
                        kf, qf[ksub], S[kb], 0, 0, 0);
                }
            }
            __builtin_amdgcn_s_setprio(0);

            // ---- causal mask (boundary tiles only) ----
            if (j0 + 63 > wr0) {
#pragma unroll
                for (int kb = 0; kb < 2; ++kb)
#pragma unroll
                    for (int r = 0; r < 16; ++r) {
                        int ka = j0 + kb * 32 + (r & 3) + 8 * (r >> 2) + 4 * hlf;
                        if (ka > qrow) S[kb][r] = -1e30f;
                    }
            }

            // ---- softmax (exp2 domain): tree max, 1 shfl, 4-way sums ----
            float mx[8];
#pragma unroll
            for (int r = 0; r < 8; ++r)
                mx[r] = fmaxf(fmaxf(S[0][r], S[0][r + 8]),
                              fmaxf(S[1][r], S[1][r + 8]));
            float m01 = fmaxf(mx[0], mx[1]), m23 = fmaxf(mx[2], mx[3]);
            float m45 = fmaxf(mx[4], mx[5]), m67 = fmaxf(mx[6], mx[7]);
            float pm = fmaxf(fmaxf(m01, m23), fmaxf(m45, m67));
            pm = fmaxf(pm, __shfl_xor(pm, 32));

            if (__any(pm > m)) {
                float mnew = fmaxf(m, pm);
                float cor  = __builtin_amdgcn_exp2f(m - mnew);
                m = mnew;
                l *= cor;
#pragma unroll
                for (int r = 0; r < 16; ++r) { O0[r] *= cor; O1[r] *= cor; }
            }

            float l0 = 0.f, l1 = 0.f, l2 = 0.f, l3 = 0.f;
#pragma unroll
            for (int kb = 0; kb < 2; ++kb)
#pragma unroll
                for (int r = 0; r < 16; r += 4) {
                    float p0 = __builtin_amdgcn_exp2f(S[kb][r + 0] - m);
                    float p1 = __builtin_amdgcn_exp2f(S[kb][r + 1] - m);
                    float p2 = __builtin_amdgcn_exp2f(S[kb][r + 2] - m);
                    float p3 = __builtin_amdgcn_exp2f(S[kb][r + 3] - m);
                    S[kb][r + 0] = p0; S[kb][r + 1] = p1;
                    S[kb][r + 2] = p2; S[kb][r + 3] = p3;
                    l0 += p0; l1 += p1; l2 += p2; l3 += p3;
                }
            l += (l0 + l1) + (l2 + l3);

            // ---- PV: O^T += V^T * P^T (cvt_pk + permlane swap) ----
#pragma unroll
            for (int kc = 0; kc < 4; ++kc) {
                const int kb = kc >> 1;
                const int R0 = (kc & 1) * 8;
                unsigned pa = cvt_pk_bf16(S[kb][R0 + 0], S[kb][R0 + 1]);
                unsigned pc = cvt_pk_bf16(S[kb][R0 + 4], S[kb][R0 + 5]);
                asm("v_permlane32_swap_b32 %0, %1" : "+v"(pa), "+v"(pc));
                unsigned pb = cvt_pk_bf16(S[kb][R0 + 2], S[kb][R0 + 3]);
                unsigned pd = cvt_pk_bf16(S[kb][R0 + 6], S[kb][R0 + 7]);
                asm("v_permlane32_swap_b32 %0, %1" : "+v"(pb), "+v"(pd));
                union { unsigned u[4]; bf16x8 v; } pf;
                pf.u[0] = pa; pf.u[1] = pb; pf.u[2] = pc; pf.u[3] = pd;
                __builtin_amdgcn_s_setprio(1);
#pragma unroll
                for (int db = 0; db < 2; ++db) {
                    const int dim = db * 32 + qcol;
                    int boff = dim * 128 + ((kc * 32 + hlf * 16) ^ ((dim & 7) << 4));
                    bf16x8 vf = *reinterpret_cast<const bf16x8*>((char*)&Vt[buf][0] + boff);
                    if (db == 0)
                        O0 = __builtin_amdgcn_mfma_f32_32x32x16_bf16(vf, pf.v, O0, 0, 0, 0);
                    else
                        O1 = __builtin_amdgcn_mfma_f32_32x32x16_bf16(vf, pf.v, O1, 0, 0, 0);
                }
                __builtin_amdgcn_s_setprio(0);
            }
        }
    }

    // ---- epilogue ----
    l += __shfl_xor(l, 32);
    const float inv = 1.f / l;
    unsigned short* crow = CTX + ((size_t)(b * SEQ + qrow)) * DMODEL + h * DHEAD;
#pragma unroll
    for (int pq = 0; pq < 4; ++pq) {
        unsigned w0 = cvt_pk_bf16(O0[pq * 4 + 0] * inv, O0[pq * 4 + 1] * inv);
        unsigned w1 = cvt_pk_bf16(O0[pq * 4 + 2] * inv, O0[pq * 4 + 3] * inv);
        uint2 val; val.x = w0; val.y = w1;
        *reinterpret_cast<uint2*>(crow + 8 * pq + 4 * hlf) = val;
    }
#pragma unroll
    for (int pq = 0; pq < 4; ++pq) {
        unsigned w0 = cvt_pk_bf16(O1[pq * 4 + 0] * inv, O1[pq * 4 + 1] * inv);
        unsigned w1 = cvt_pk_bf16(O1[pq * 4 + 2] * inv, O1[pq * 4 + 3] * inv);
        uint2 val; val.x = w0; val.y = w1;
        *reinterpret_cast<uint2*>(crow + 32 + 8 * pq + 4 * hlf) = val;
    }
}

// ---------------------------------------------------------------------------
extern "C" void kernel_launch(void* const* d_in, const int* in_sizes, int n_in,
                              void* d_out, int out_size, void* d_ws, size_t ws_size,
                              hipStream_t stream) {
    const float* hs = (const float*)d_in[0];
    const float* Wq = (const float*)d_in[1];
    const float* bq = (const float*)d_in[2];
    const float* Wk = (const float*)d_in[3];
    const float* bk = (const float*)d_in[4];
    const float* Wv = (const float*)d_in[5];
    const float* bv = (const float*)d_in[6];
    const float* Wo = (const float*)d_in[7];
    const float* bo = (const float*)d_in[8];
    float* out = (float*)d_out;

    const size_t NTOK = (size_t)NBATCH * SEQ;        // 4096
    unsigned short* hs_bf  = (unsigned short*)d_ws;              // 8 MB
    unsigned short* Wqkv_t = hs_bf + NTOK * DMODEL;              // 6 MB [3072][1024]
    unsigned short* Wo_t   = Wqkv_t + 3072 * 1024;               // 2 MB [1024][1024]
    unsigned short* Qh     = Wo_t + 1024 * 1024;                 // 8 MB [B,H,S,64]
    unsigned short* Kh     = Qh + NTOK * DMODEL;                 // 8 MB
    unsigned short* Vt     = Kh + NTOK * DMODEL;                 // 8 MB [B,H,64,S]
    unsigned short* Cb     = Vt + NTOK * DMODEL;                 // 8 MB ctx bf16

    cast_bf16_kernel<<<(int)(NTOK * DMODEL / 8 / 256), 256, 0, stream>>>(hs, hs_bf);
    wt_cast4_kernel<<<dim3(256, 4), 256, 0, stream>>>(Wq, Wk, Wv, Wo, Wqkv_t);

    dim3 gqkv(3072 / 128, NTOK / 128);               // (24, 32)
    gemm_bf16<0><<<gqkv, 256, 0, stream>>>(hs_bf, Wqkv_t, bq, bk, bv,
                                           nullptr, Qh, Kh, Vt,
                                           (int)NTOK, 3072, DMODEL);

    attn_mfma_kernel<<<NBATCH * NHEADS * (SEQ / 128), 256, 0, stream>>>(Qh, Kh, Vt, Cb);

    dim3 go(DMODEL / 128, NTOK / 128);               // (8, 32)
    gemm_bf16<1><<<go, 256, 0, stream>>>(Cb, Wo_t, bo, nullptr, nullptr,
                                         out, nullptr, nullptr, nullptr,
                                         (int)NTOK, DMODEL, DMODEL);
}

// Round 8
// 133.555 us; speedup vs baseline: 1.1513x; 1.0092x over previous
//
#include <hip/hip_runtime.h>
#include <math.h>

#define SEQ    2048
#define DMODEL 1024
#define NHEADS 16
#define DHEAD  64
#define NBATCH 2

typedef __attribute__((ext_vector_type(8)))  short bf16x8;
typedef __attribute__((ext_vector_type(4)))  float f32x4;
typedef __attribute__((ext_vector_type(16))) float f32x16;

__device__ __forceinline__ unsigned short f2bf(float f) {
    union { float f; unsigned u; } v; v.f = f;
    unsigned r = (v.u + 0x7FFF + ((v.u >> 16) & 1)) >> 16;
    return (unsigned short)r;
}

__device__ __forceinline__ unsigned cvt_pk_bf16(float lo, float hi) {
    unsigned r;
    asm("v_cvt_pk_bf16_f32 %0, %1, %2" : "=v"(r) : "v"(lo), "v"(hi));
    return r;
}

// async global->LDS, 16B per lane
__device__ __forceinline__ void gload16(const void* g, void* l) {
    __builtin_amdgcn_global_load_lds(
        (const __attribute__((address_space(1))) unsigned*)g,
        (__attribute__((address_space(3))) unsigned*)l, 16, 0, 0);
}

// ---------------------------------------------------------------------------
// Cast fp32 -> bf16, flat contiguous. 8 elems/thread.
// ---------------------------------------------------------------------------
__global__ __launch_bounds__(256)
void cast_bf16_kernel(const float* __restrict__ in, unsigned short* __restrict__ out) {
    const size_t g8 = ((size_t)blockIdx.x * 256 + threadIdx.x) * 8;
    float4 a = *reinterpret_cast<const float4*>(in + g8);
    float4 b = *reinterpret_cast<const float4*>(in + g8 + 4);
    bf16x8 o;
    o[0] = (short)f2bf(a.x); o[1] = (short)f2bf(a.y);
    o[2] = (short)f2bf(a.z); o[3] = (short)f2bf(a.w);
    o[4] = (short)f2bf(b.x); o[5] = (short)f2bf(b.y);
    o[6] = (short)f2bf(b.z); o[7] = (short)f2bf(b.w);
    *reinterpret_cast<bf16x8*>(out + g8) = o;
}

// ---------------------------------------------------------------------------
// Transpose-cast all four 1024x1024 fp32 weights [K][N] -> bf16 [N][K].
// ---------------------------------------------------------------------------
__global__ __launch_bounds__(256)
void wt_cast4_kernel(const float* __restrict__ W0, const float* __restrict__ W1,
                     const float* __restrict__ W2, const float* __restrict__ W3,
                     unsigned short* __restrict__ out) {
    __shared__ float tile[64][65];
    const int wsel = blockIdx.y;
    const float* W = (wsel == 0) ? W0 : (wsel == 1) ? W1 : (wsel == 2) ? W2 : W3;
    unsigned short* Wt = out + (size_t)wsel * 1024 * 1024;

    const int nt  = blockIdx.x & 15;
    const int kt  = blockIdx.x >> 4;
    const int tid = threadIdx.x;

#pragma unroll
    for (int r = 0; r < 4; ++r) {
        int kl = r * 16 + (tid >> 4);
        int nl = (tid & 15) * 4;
        float4 v = *reinterpret_cast<const float4*>(
            &W[(size_t)(kt * 64 + kl) * 1024 + nt * 64 + nl]);
        tile[kl][nl + 0] = v.x; tile[kl][nl + 1] = v.y;
        tile[kl][nl + 2] = v.z; tile[kl][nl + 3] = v.w;
    }
    __syncthreads();

    const int n  = tid >> 2;
    const int kc = (tid & 3) * 16;
    bf16x8 o0, o1;
#pragma unroll
    for (int i = 0; i < 8; ++i) o0[i] = (short)f2bf(tile[kc + i][n]);
#pragma unroll
    for (int i = 0; i < 8; ++i) o1[i] = (short)f2bf(tile[kc + 8 + i][n]);
    unsigned short* op = Wt + (size_t)(nt * 64 + n) * 1024 + kt * 64 + kc;
    *reinterpret_cast<bf16x8*>(op)     = o0;
    *reinterpret_cast<bf16x8*>(op + 8) = o1;
}

// ---------------------------------------------------------------------------
// bf16 MFMA GEMM (unchanged from R7): 128x128, BK=32, gload_lds(16B),
// double-buffered LDS, 2-phase pipeline, involutive chunk-XOR swizzle.
// ---------------------------------------------------------------------------
template <int MODE>
__global__ __launch_bounds__(256)
void gemm_bf16(const unsigned short* __restrict__ A,
               const unsigned short* __restrict__ Bt,
               const float* __restrict__ bias0, const float* __restrict__ bias1,
               const float* __restrict__ bias2,
               float* __restrict__ Cf,
               unsigned short* __restrict__ Qo, unsigned short* __restrict__ Ko,
               unsigned short* __restrict__ Vo,
               int M, int N, int K) {
    __shared__ unsigned short As[2][128 * 32];
    __shared__ unsigned short Bs[2][128 * 32];

    const int tid  = threadIdx.x;
    const int bm   = blockIdx.y * 128;
    const int bn   = blockIdx.x * 128;
    const int w    = tid >> 6;
    const int lane = tid & 63;
    const int lrow = lane & 15;
    const int lk   = lane >> 4;
    const int wm0  = (w >> 1) * 64;
    const int wn0  = (w & 1) * 64;

    const int boff0 = tid * 16;
    const int boff1 = 4096 + tid * 16;
    const int row0  = tid >> 2;
    const int row1  = 64 + row0;
    const int c     = tid & 3;
    const int sw0   = (c ^ ((row0 >> 1) & 3)) * 8;
    const int sw1   = (c ^ ((row1 >> 1) & 3)) * 8;

    const unsigned short* Ag = A  + (size_t)bm * K;
    const unsigned short* Bg = Bt + (size_t)bn * K;

    f32x4 acc[4][4];
#pragma unroll
    for (int i = 0; i < 4; ++i)
#pragma unroll
        for (int j = 0; j < 4; ++j) acc[i][j] = (f32x4){0.f, 0.f, 0.f, 0.f};

    const int NT = K / 32;
    gload16(Ag + (size_t)row0 * K + sw0, (char*)&As[0][0] + boff0);
    gload16(Ag + (size_t)row1 * K + sw1, (char*)&As[0][0] + boff1);
    gload16(Bg + (size_t)row0 * K + sw0, (char*)&Bs[0][0] + boff0);
    gload16(Bg + (size_t)row1 * K + sw1, (char*)&Bs[0][0] + boff1);
    __syncthreads();

    int buf = 0;
    for (int kt = 0; kt < NT; ++kt) {
        if (kt + 1 < NT) {
            const int k0 = (kt + 1) * 32;
            gload16(Ag + (size_t)row0 * K + k0 + sw0, (char*)&As[buf ^ 1][0] + boff0);
            gload16(Ag + (size_t)row1 * K + k0 + sw1, (char*)&As[buf ^ 1][0] + boff1);
            gload16(Bg + (size_t)row0 * K + k0 + sw0, (char*)&Bs[buf ^ 1][0] + boff0);
            gload16(Bg + (size_t)row1 * K + k0 + sw1, (char*)&Bs[buf ^ 1][0] + boff1);
        }

        bf16x8 af[4], bf[4];
#pragma unroll
        for (int mg = 0; mg < 4; ++mg) {
            const int r = wm0 + mg * 16 + lrow;
            af[mg] = *reinterpret_cast<const bf16x8*>(
                (char*)&As[buf][0] + r * 64 + ((lk ^ ((r >> 1) & 3)) * 16));
        }
#pragma unroll
        for (int ng = 0; ng < 4; ++ng) {
            const int r = wn0 + ng * 16 + lrow;
            bf[ng] = *reinterpret_cast<const bf16x8*>(
                (char*)&Bs[buf][0] + r * 64 + ((lk ^ ((r >> 1) & 3)) * 16));
        }
#pragma unroll
        for (int mg = 0; mg < 4; ++mg)
#pragma unroll
            for (int ng = 0; ng < 4; ++ng)
                acc[mg][ng] = __builtin_amdgcn_mfma_f32_16x16x32_bf16(
                    af[mg], bf[ng], acc[mg][ng], 0, 0, 0);

        __syncthreads();
        buf ^= 1;
    }

    if (MODE == 0) {
        const int type = bn >> 10;
        const int nloc = bn & 1023;
        const float* bias = (type == 0) ? bias0 : (type == 1) ? bias1 : bias2;
        const float QSCALE = 0.125f * 1.44269504088896f;
#pragma unroll
        for (int ng = 0; ng < 4; ++ng) {
            const int col = nloc + wn0 + ng * 16 + lrow;
            const float bv = bias[col];
            const int h = col >> 6, d = col & 63;
#pragma unroll
            for (int mg = 0; mg < 4; ++mg) {
#pragma unroll
                for (int j = 0; j < 4; ++j) {
                    const int row = bm + wm0 + mg * 16 + lk * 4 + j;
                    const int b = row >> 11, s = row & 2047;
                    const float val = acc[mg][ng][j] + bv;
                    if (type == 0)
                        Qo[((size_t)(b * 16 + h) * SEQ + s) * 64 + d] = f2bf(val * QSCALE);
                    else if (type == 1)
                        Ko[((size_t)(b * 16 + h) * SEQ + s) * 64 + d] = f2bf(val);
                    else
                        Vo[((size_t)(b * 16 + h) * 64 + d) * SEQ + s] = f2bf(val);
                }
            }
        }
    } else {
#pragma unroll
        for (int ng = 0; ng < 4; ++ng) {
            const int col = bn + wn0 + ng * 16 + lrow;
            const float bv = bias0[col];
#pragma unroll
            for (int mg = 0; mg < 4; ++mg) {
#pragma unroll
                for (int j = 0; j < 4; ++j) {
                    const int row = bm + wm0 + mg * 16 + lk * 4 + j;
                    Cf[(size_t)row * N + col] = acc[mg][ng][j] + bv;
                }
            }
        }
    }
}

// ---------------------------------------------------------------------------
// Causal flash attention, swapped-operand 32x32x16 MFMA.
// R8: 512-thread blocks, 8 waves = 4 row-groups x 2 KEY-PARITIES. Each
// parity wave processes alternate 64-key tiles of a 128-key chunk with its
// own (m,l,O); exact LDS merge at the end. Doubles waves/SIMD (2->4),
// halves barrier count. XCD head-grouping (FETCH 12MB, R6-proven) +
// CORRECT pair balance: co-resident pair (k,k+8) -> rb (a,15-a) ->
// chunk counts sum to 17 for every pair.
// ---------------------------------------------------------------------------
__global__ __launch_bounds__(512, 4)
void attn_mfma_kernel(const unsigned short* __restrict__ Qg,
                      const unsigned short* __restrict__ Kg,
                      const unsigned short* __restrict__ Vtg,
                      unsigned short* __restrict__ CTX) {
    // [buf(2) x (K 16KB | V 16KB)] = 64KB; merge overlay uses first 36.9KB
    __shared__ __align__(16) char smem[65536];

    const int bid = blockIdx.x;           // 0..511
    const int xcd = bid & 7;
    const int s   = bid >> 3;             // 0..63
    const int bh  = xcd * 4 + (s & 3);    // 4 heads per XCD (L2-resident K/V)
    const int k   = s >> 2;               // 0..15
    const int rb  = (k < 8) ? k : (23 - k);   // pair (k,k+8)->(a,15-a)
    const int b  = bh >> 4;
    const int h  = bh & 15;
    const int r0 = rb * 128;
    const int tid  = threadIdx.x;
    const int w    = tid >> 6;            // 0..7
    const int wrow = w & 3;               // row-group
    const int wkey = w >> 2;              // key parity
    const int lane = tid & 63;
    const int qcol = lane & 31;
    const int hlf  = lane >> 5;
    const int wr0  = r0 + wrow * 32;
    const int qrow = wr0 + qcol;

    const unsigned short* Kb = Kg + ((size_t)bh * SEQ) * DHEAD;
    const unsigned short* Vb = Vtg + ((size_t)bh * DHEAD) * SEQ;

    // Q fragment (B-operand)
    bf16x8 qf[4];
    {
        const unsigned short* qp = Qg + ((size_t)bh * SEQ + qrow) * DHEAD + hlf * 8;
#pragma unroll
        for (int ksub = 0; ksub < 4; ++ksub)
            qf[ksub] = *reinterpret_cast<const bf16x8*>(qp + ksub * 16);
    }

    f32x16 O0, O1;
#pragma unroll
    for (int r = 0; r < 16; ++r) { O0[r] = 0.f; O1[r] = 0.f; }
    float m = -1e30f, l = 0.f;

    // staging geometry: 512 threads cover 2 tiles (128 keys) of K and V.
    const int srow  = tid >> 3;          // 0..63 (row within tile, both p)
    const int slot  = tid & 7;           // 16B slot
    const int swz   = (slot * 16) ^ ((srow & 7) << 4);
    const int dK0   = srow * 128 + swz;            // K tile p=0
    const int dK1   = 8192 + srow * 128 + swz;     // K tile p=1
    const int dV0   = 16384 + srow * 128 + swz;    // V tile p=0 (srow=dim)
    const int dV1   = 24576 + srow * 128 + swz;

    // prologue: load chunk 0 (keys 0..127) into regs
    bf16x8 rk0, rk1, rv0, rv1;
    {
        rk0 = *reinterpret_cast<const bf16x8*>(Kb + (size_t)srow * DHEAD + slot * 8);
        rk1 = *reinterpret_cast<const bf16x8*>(Kb + (size_t)(64 + srow) * DHEAD + slot * 8);
        rv0 = *reinterpret_cast<const bf16x8*>(Vb + (size_t)srow * SEQ + slot * 8);
        rv1 = *reinterpret_cast<const bf16x8*>(Vb + (size_t)srow * SEQ + 64 + slot * 8);
    }

    const int nit = rb + 1;              // 128-key chunks
    for (int it = 0; it < nit; ++it) {
        const int jc  = it * 128;
        const int buf = (it & 1) * 32768;
        // commit staged regs to LDS[buf]
        *reinterpret_cast<bf16x8*>(smem + buf + dK0) = rk0;
        *reinterpret_cast<bf16x8*>(smem + buf + dK1) = rk1;
        *reinterpret_cast<bf16x8*>(smem + buf + dV0) = rv0;
        *reinterpret_cast<bf16x8*>(smem + buf + dV1) = rv1;
        __syncthreads();
        // issue next chunk's loads (hidden under compute)
        if (it + 1 < nit) {
            const int j1 = jc + 128;
            rk0 = *reinterpret_cast<const bf16x8*>(Kb + (size_t)(j1 + srow) * DHEAD + slot * 8);
            rk1 = *reinterpret_cast<const bf16x8*>(Kb + (size_t)(j1 + 64 + srow) * DHEAD + slot * 8);
            rv0 = *reinterpret_cast<const bf16x8*>(Vb + (size_t)srow * SEQ + j1 + slot * 8);
            rv1 = *reinterpret_cast<const bf16x8*>(Vb + (size_t)srow * SEQ + j1 + 64 + slot * 8);
        }

        const int j0 = jc + wkey * 64;        // this wave's tile
        if (j0 <= wr0 + 31) {
            const int tb = buf + wkey * 8192; // K tile base
            // ---- S^T = K * Q^T ----
            f32x16 S[2];
#pragma unroll
            for (int r = 0; r < 16; ++r) { S[0][r] = 0.f; S[1][r] = 0.f; }
            __builtin_amdgcn_s_setprio(1);
#pragma unroll
            for (int kb = 0; kb < 2; ++kb) {
                const int key = kb * 32 + qcol;
#pragma unroll
                for (int ksub = 0; ksub < 4; ++ksub) {
                    int boff = tb + key * 128 + ((ksub * 32 + hlf * 16) ^ ((key & 7) << 4));
                    bf16x8 kf = *reinterpret_cast<const bf16x8*>(smem + boff);
                    S[kb] = __builtin_amdgcn_mfma_f32_32x32x16_bf16(
                        kf, qf[ksub], S[kb], 0, 0, 0);
                }
            }
            __builtin_amdgcn_s_setprio(0);

            // ---- causal mask (boundary tiles only) ----
            if (j0 + 63 > wr0) {
#pragma unroll
                for (int kb = 0; kb < 2; ++kb)
#pragma unroll
                    for (int r = 0; r < 16; ++r) {
                        int ka = j0 + kb * 32 + (r & 3) + 8 * (r >> 2) + 4 * hlf;
                        if (ka > qrow) S[kb][r] = -1e30f;
                    }
            }

            // ---- softmax (exp2 domain) ----
            float mx[8];
#pragma unroll
            for (int r = 0; r < 8; ++r)
                mx[r] = fmaxf(fmaxf(S[0][r], S[0][r + 8]),
                              fmaxf(S[1][r], S[1][r + 8]));
            float m01 = fmaxf(mx[0], mx[1]), m23 = fmaxf(mx[2], mx[3]);
            float m45 = fmaxf(mx[4], mx[5]), m67 = fmaxf(mx[6], mx[7]);
            float pm = fmaxf(fmaxf(m01, m23), fmaxf(m45, m67));
            pm = fmaxf(pm, __shfl_xor(pm, 32));

            if (__any(pm > m)) {
                float mnew = fmaxf(m, pm);
                float cor  = __builtin_amdgcn_exp2f(m - mnew);
                m = mnew;
                l *= cor;
#pragma unroll
                for (int r = 0; r < 16; ++r) { O0[r] *= cor; O1[r] *= cor; }
            }

            float l0 = 0.f, l1 = 0.f, l2 = 0.f, l3 = 0.f;
#pragma unroll
            for (int kb = 0; kb < 2; ++kb)
#pragma unroll
                for (int r = 0; r < 16; r += 4) {
                    float p0 = __builtin_amdgcn_exp2f(S[kb][r + 0] - m);
                    float p1 = __builtin_amdgcn_exp2f(S[kb][r + 1] - m);
                    float p2 = __builtin_amdgcn_exp2f(S[kb][r + 2] - m);
                    float p3 = __builtin_amdgcn_exp2f(S[kb][r + 3] - m);
                    S[kb][r + 0] = p0; S[kb][r + 1] = p1;
                    S[kb][r + 2] = p2; S[kb][r + 3] = p3;
                    l0 += p0; l1 += p1; l2 += p2; l3 += p3;
                }
            l += (l0 + l1) + (l2 + l3);

            // ---- PV: O^T += V^T * P^T ----
            const int vb2 = buf + 16384 + wkey * 8192;
#pragma unroll
            for (int kc = 0; kc < 4; ++kc) {
                const int kb = kc >> 1;
                const int R0 = (kc & 1) * 8;
                unsigned pa = cvt_pk_bf16(S[kb][R0 + 0], S[kb][R0 + 1]);
                unsigned pc = cvt_pk_bf16(S[kb][R0 + 4], S[kb][R0 + 5]);
                asm("v_permlane32_swap_b32 %0, %1" : "+v"(pa), "+v"(pc));
                unsigned pb = cvt_pk_bf16(S[kb][R0 + 2], S[kb][R0 + 3]);
                unsigned pd = cvt_pk_bf16(S[kb][R0 + 6], S[kb][R0 + 7]);
                asm("v_permlane32_swap_b32 %0, %1" : "+v"(pb), "+v"(pd));
                union { unsigned u[4]; bf16x8 v; } pf;
                pf.u[0] = pa; pf.u[1] = pb; pf.u[2] = pc; pf.u[3] = pd;
                __builtin_amdgcn_s_setprio(1);
#pragma unroll
                for (int db = 0; db < 2; ++db) {
                    const int dim = db * 32 + qcol;
                    int boff = vb2 + dim * 128 + ((kc * 32 + hlf * 16) ^ ((dim & 7) << 4));
                    bf16x8 vf = *reinterpret_cast<const bf16x8*>(smem + boff);
                    if (db == 0)
                        O0 = __builtin_amdgcn_mfma_f32_32x32x16_bf16(vf, pf.v, O0, 0, 0, 0);
                    else
                        O1 = __builtin_amdgcn_mfma_f32_32x32x16_bf16(vf, pf.v, O1, 0, 0, 0);
                }
                __builtin_amdgcn_s_setprio(0);
            }
        }
    }

    // ---- merge key-parities (exact): wkey=1 publishes, wkey=0 combines ----
    __syncthreads();
    float* mb = (float*)smem;
    if (wkey == 1) {
        float* dst = mb + ((size_t)(wrow * 64 + lane)) * 36;
        dst[0] = m; dst[1] = l;
#pragma unroll
        for (int r = 0; r < 16; ++r) dst[2 + r]  = O0[r];
#pragma unroll
        for (int r = 0; r < 16; ++r) dst[18 + r] = O1[r];
    }
    __syncthreads();
    if (wkey == 0) {
        const float* src = mb + ((size_t)(wrow * 64 + lane)) * 36;
        float mB = src[0], lB = src[1];
        float mf = fmaxf(m, mB);
        float sA = __builtin_amdgcn_exp2f(m - mf);
        float sB = __builtin_amdgcn_exp2f(mB - mf);
        l = l * sA + lB * sB;
#pragma unroll
        for (int r = 0; r < 16; ++r) O0[r] = O0[r] * sA + src[2 + r]  * sB;
#pragma unroll
        for (int r = 0; r < 16; ++r) O1[r] = O1[r] * sA + src[18 + r] * sB;

        l += __shfl_xor(l, 32);
        const float inv = 1.f / l;
        unsigned short* crow = CTX + ((size_t)(b * SEQ + qrow)) * DMODEL + h * DHEAD;
#pragma unroll
        for (int pq = 0; pq < 4; ++pq) {
            unsigned w0 = cvt_pk_bf16(O0[pq * 4 + 0] * inv, O0[pq * 4 + 1] * inv);
            unsigned w1 = cvt_pk_bf16(O0[pq * 4 + 2] * inv, O0[pq * 4 + 3] * inv);
            uint2 val; val.x = w0; val.y = w1;
            *reinterpret_cast<uint2*>(crow + 8 * pq + 4 * hlf) = val;
        }
#pragma unroll
        for (int pq = 0; pq < 4; ++pq) {
            unsigned w0 = cvt_pk_bf16(O1[pq * 4 + 0] * inv, O1[pq * 4 + 1] * inv);
            unsigned w1 = cvt_pk_bf16(O1[pq * 4 + 2] * inv, O1[pq * 4 + 3] * inv);
            uint2 val; val.x = w0; val.y = w1;
            *reinterpret_cast<uint2*>(crow + 32 + 8 * pq + 4 * hlf) = val;
        }
    }
}

// ---------------------------------------------------------------------------
extern "C" void kernel_launch(void* const* d_in, const int* in_sizes, int n_in,
                              void* d_out, int out_size, void* d_ws, size_t ws_size,
                              hipStream_t stream) {
    const float* hs = (const float*)d_in[0];
    const float* Wq = (const float*)d_in[1];
    const float* bq = (const float*)d_in[2];
    const float* Wk = (const float*)d_in[3];
    const float* bk = (const float*)d_in[4];
    const float* Wv = (const float*)d_in[5];
    const float* bv = (const float*)d_in[6];
    const float* Wo = (const float*)d_in[7];
    const float* bo = (const float*)d_in[8];
    float* out = (float*)d_out;

    const size_t NTOK = (size_t)NBATCH * SEQ;        // 4096
    unsigned short* hs_bf  = (unsigned short*)d_ws;              // 8 MB
    unsigned short* Wqkv_t = hs_bf + NTOK * DMODEL;              // 6 MB [3072][1024]
    unsigned short* Wo_t   = Wqkv_t + 3072 * 1024;               // 2 MB [1024][1024]
    unsigned short* Qh     = Wo_t + 1024 * 1024;                 // 8 MB [B,H,S,64]
    unsigned short* Kh     = Qh + NTOK * DMODEL;                 // 8 MB
    unsigned short* Vt     = Kh + NTOK * DMODEL;                 // 8 MB [B,H,64,S]
    unsigned short* Cb     = Vt + NTOK * DMODEL;                 // 8 MB ctx bf16

    cast_bf16_kernel<<<(int)(NTOK * DMODEL / 8 / 256), 256, 0, stream>>>(hs, hs_bf);
    wt_cast4_kernel<<<dim3(256, 4), 256, 0, stream>>>(Wq, Wk, Wv, Wo, Wqkv_t);

    dim3 gqkv(3072 / 128, NTOK / 128);               // (24, 32)
    gemm_bf16<0><<<gqkv, 256, 0, stream>>>(hs_bf, Wqkv_t, bq, bk, bv,
                                           nullptr, Qh, Kh, Vt,
                                           (int)NTOK, 3072, DMODEL);

    attn_mfma_kernel<<<512, 512, 0, stream>>>(Qh, Kh, Vt, Cb);

    dim3 go(DMODEL / 128, NTOK / 128);               // (8, 32)
    gemm_bf16<1><<<go, 256, 0, stream>>>(Cb, Wo_t, bo, nullptr, nullptr,
                                         out, nullptr, nullptr, nullptr,
                                         (int)NTOK, DMODEL, DMODEL);
}